// Round 1
// baseline (241.512 us; speedup 1.0000x reference)
//
#include <hip/hip_runtime.h>
#include <hip/hip_fp16.h>

#define BB 4
#define CC 3
#define HH 384
#define WW 384
#define HW (HH * WW)
#define KK 5
#define RR 2
#define K2 25
#define NITER 20
#define PADF 2048   // guard floats around each x buffer (max OOB reach is 772)

static constexpr float INV_Z2 = 1.0f / (0.15f * 0.15f);

// ---------------------------------------------------------------------------
// prep: 2 px/thread. Per-pixel 5x5 normalized affinity -> fp16 planes
// wgt[b][t][pix], plus x0 = feat*mask. OOB taps are exactly 0 (the +10 shift
// makes the exponent ~-1.3e4 -> fp32 exp underflows to +0), so iter kernels
// can read x branch-free through padded guards.
// ---------------------------------------------------------------------------
__global__ __launch_bounds__(256) void prep2(
    const float* __restrict__ img, const float* __restrict__ feat,
    const float* __restrict__ mask, __half* __restrict__ wgt,
    float* __restrict__ x0)
{
    int gid = blockIdx.x * 256 + threadIdx.x;
    int p0 = gid * 2;
    if (p0 >= BB * HW) return;
    int b   = p0 / HW;
    int rem = p0 - b * HW;          // even
    int h   = rem / WW;
    int wc  = rem - h * WW;

    const float* imgb = img + (size_t)b * CC * HW;
    const size_t bHW = (size_t)b * HW;

    float2 f  = *(const float2*)(feat + bHW + rem);
    float2 mk = *(const float2*)(mask + bHW + rem);
    *(float2*)(x0 + bHW + rem) = make_float2(f.x * mk.x, f.y * mk.y);

    float v0[2], v1[2], v2[2];
#pragma unroll
    for (int s = 0; s < 2; ++s) {
        v0[s] = imgb[0 * HW + rem + s] + 10.f;
        v1[s] = imgb[1 * HW + rem + s] + 10.f;
        v2[s] = imgb[2 * HW + rem + s] + 10.f;
    }

    float a[2][K2];
    float sz[2] = {1e-10f, 1e-10f};
#pragma unroll
    for (int t = 0; t < K2; ++t) {
        int dr = t / KK - RR, dc = t % KK - RR;
        int rr = h + dr;
#pragma unroll
        for (int s = 0; s < 2; ++s) {
            int cc2 = wc + s + dc;
            float av = 0.f;
            if (rr >= 0 && rr < HH && cc2 >= 0 && cc2 < WW) {
                int q = rr * WW + cc2;
                float d0 = imgb[0 * HW + q] + 10.f - v0[s];
                float d1 = imgb[1 * HW + q] + 10.f - v1[s];
                float d2 = imgb[2 * HW + q] + 10.f - v2[s];
                av = __expf(-(d0 * d0 + d1 * d1 + d2 * d2) * INV_Z2);
            }
            a[s][t] = av;
            sz[s] += av;
        }
    }
    float i0 = 1.f / sz[0], i1 = 1.f / sz[1];
#pragma unroll
    for (int t = 0; t < K2; ++t) {
        __half2 hv = __floats2half2_rn(a[0][t] * i0, a[1][t] * i1);
        *(__half2*)(wgt + ((size_t)b * K2 + t) * HW + rem) = hv;
    }
}

// ---------------------------------------------------------------------------
// One iteration, 2 px/thread. 4x the wave count of the old 8 px/thread
// version (1152 blocks -> ~18 waves/CU) so cache-hit latency is hidden by
// TLP instead of being exposed at ~1 wave/SIMD. All loads aligned:
// x rows via 3x float2 (rem even), weights via half2, mask/store float2.
// Branch-free: OOB x reads land in guard pads / neighboring rows and are
// multiplied by exactly-zero weights.
// ---------------------------------------------------------------------------
__global__ __launch_bounds__(256) void iter2(
    const __half* __restrict__ wgt, const float* __restrict__ xin,
    const float* __restrict__ mask, float* __restrict__ xout)
{
    int gid = blockIdx.x * 256 + threadIdx.x;
    int p0 = gid * 2;                      // grid sized exactly: p0 < BB*HW
    int b   = p0 / HW;
    int rem = p0 - b * HW;                 // even
    const size_t bHW = (size_t)b * HW;

    const float*  xb = xin + bHW;
    const __half* wb = wgt + (size_t)b * K2 * HW + rem;

    float acc0 = 0.f, acc1 = 0.f;
#pragma unroll
    for (int dr = -2; dr <= 2; ++dr) {
        // x row h+dr, cols c0-2 .. c0+3: three aligned float2 loads
        const float* p = xb + rem + dr * WW - 2;
        float xs[6];
        float2 u0 = *(const float2*)(p);
        float2 u1 = *(const float2*)(p + 2);
        float2 u2 = *(const float2*)(p + 4);
        xs[0] = u0.x; xs[1] = u0.y;
        xs[2] = u1.x; xs[3] = u1.y;
        xs[4] = u2.x; xs[5] = u2.y;
#pragma unroll
        for (int dc = 0; dc < 5; ++dc) {
            const int t = (dr + 2) * 5 + dc;
            float2 w = __half22float2(*(const __half2*)(wb + (size_t)t * HW));
            acc0 = fmaf(w.x, xs[dc],     acc0);
            acc1 = fmaf(w.y, xs[dc + 1], acc1);
        }
    }
    float2 m = *(const float2*)(mask + bHW + rem);
    *(float2*)(xout + bHW + rem) = make_float2(acc0 * m.x, acc1 * m.y);
}

extern "C" void kernel_launch(void* const* d_in, const int* in_sizes, int n_in,
                              void* d_out, int out_size, void* d_ws, size_t ws_size,
                              hipStream_t stream)
{
    const float* img  = (const float*)d_in[0];
    const float* feat = (const float*)d_in[1];
    const float* mask = (const float*)d_in[2];
    float* out = (float*)d_out;

    // ws layout: [ wgt: B*25*HW halves (~29.5 MB) | PADF | xa | PADF | xb | PADF ]
    __half* wgt = (__half*)d_ws;
    float* fbase = (float*)((char*)d_ws + ((size_t)BB * K2 * HW * sizeof(__half) + 255 & ~(size_t)255));
    float* xa = fbase + PADF;
    float* xb = xa + (size_t)BB * HW + PADF;

    const int n = BB * HW;
    prep2<<<(n / 2 + 255) / 256, 256, 0, stream>>>(img, feat, mask, wgt, xa);

    const int iblocks = n / 2 / 256;   // 1152, exact
    float* cur = xa;
    float* nxt = xb;
    for (int it = 0; it < NITER - 1; ++it) {
        iter2<<<iblocks, 256, 0, stream>>>(wgt, cur, mask, nxt);
        float* t = cur; cur = nxt; nxt = t;
    }
    iter2<<<iblocks, 256, 0, stream>>>(wgt, cur, mask, out);
}

// Round 3
// 218.834 us; speedup vs baseline: 1.1036x; 1.1036x over previous
//
#include <hip/hip_runtime.h>
#include <hip/hip_fp16.h>

#define BB 4
#define CC 3
#define HH 384
#define WW 384
#define HW (HH * WW)
#define NP (BB * HW)     // pixels per plane (589824)
#define KK 5
#define RR 2
#define K2 25
#define NITER 20
#define PADF 2048        // guard floats around each x buffer (max OOB reach is 772)
#define GUARDH 1024      // guard halves before plane region (max back-reach 770)
#define GRID 1152        // blocks per launch, 2 px/thread, exact cover
#define CPX (GRID / 8)   // 144 blocks per XCD chunk

static constexpr float INV_Z2 = 1.0f / (0.15f * 0.15f);

// XCD-chunked bijective swizzle (GRID % 8 == 0). Consecutive hardware
// round-robin blocks -> same-XCD contiguous pixel chunks, stable across all
// launches, so each XCD's ~2.7 MB slice (12 fp16 planes + invm + x) stays in
// its private 4 MB L2. Same mapping in prep and iter so the producer XCD is
// the consumer XCD.
__device__ __forceinline__ int swz_bid() {
    return (blockIdx.x & 7) * CPX + (blockIdx.x >> 3);
}

// ---------------------------------------------------------------------------
// prep: 2 px/thread. Affinity a(p,q)=exp(-||I(p)-I(q)||^2/z^2) is EXACTLY
// symmetric in fp ((a+10)-(b+10) negates exactly; squares identical), and the
// center tap is exactly 1. So store only the 12 lex-positive UNNORMALIZED
// planes as fp16 plus invm = mask/sumz as fp32. OOB taps store exactly 0.
// ---------------------------------------------------------------------------
__global__ __launch_bounds__(256) void prep_sym(
    const float* __restrict__ img, const float* __restrict__ feat,
    const float* __restrict__ mask, __half* __restrict__ planes,
    float* __restrict__ invm, float* __restrict__ x0)
{
    int gid = swz_bid() * 256 + threadIdx.x;
    int p0 = gid * 2;
    int b   = p0 / HW;
    int rem = p0 - b * HW;          // even
    int h   = rem / WW;
    int wc  = rem - h * WW;

    const float* imgb = img + (size_t)b * CC * HW;
    const size_t bHW = (size_t)b * HW;

    float2 f  = *(const float2*)(feat + bHW + rem);
    float2 mk = *(const float2*)(mask + bHW + rem);
    *(float2*)(x0 + bHW + rem) = make_float2(f.x * mk.x, f.y * mk.y);

    float v0[2], v1[2], v2[2];
#pragma unroll
    for (int s = 0; s < 2; ++s) {
        v0[s] = imgb[0 * HW + rem + s] + 10.f;
        v1[s] = imgb[1 * HW + rem + s] + 10.f;
        v2[s] = imgb[2 * HW + rem + s] + 10.f;
    }

    float a[2][K2];
    float sz[2] = {1e-10f, 1e-10f};
#pragma unroll
    for (int t = 0; t < K2; ++t) {
        int dr = t / KK - RR, dc = t % KK - RR;
        int rr = h + dr;
#pragma unroll
        for (int s = 0; s < 2; ++s) {
            int cc2 = wc + s + dc;
            float av = 0.f;
            if (rr >= 0 && rr < HH && cc2 >= 0 && cc2 < WW) {
                int q = rr * WW + cc2;
                float d0 = imgb[0 * HW + q] + 10.f - v0[s];
                float d1 = imgb[1 * HW + q] + 10.f - v1[s];
                float d2 = imgb[2 * HW + q] + 10.f - v2[s];
                av = __expf(-(d0 * d0 + d1 * d1 + d2 * d2) * INV_Z2);
            }
            a[s][t] = av;
            sz[s] += av;
        }
    }
    float i0 = 1.f / sz[0], i1 = 1.f / sz[1];
    *(float2*)(invm + bHW + rem) = make_float2(mk.x * i0, mk.y * i1);

    // store the 12 lex-positive taps (t = 13..24), unnormalized
#pragma unroll
    for (int t = 13; t < K2; ++t) {
        __half2 hv = __floats2half2_rn(a[0][t], a[1][t]);
        *(__half2*)(planes + (size_t)(t - 13) * NP + bHW + rem) = hv;
    }
}

// ---------------------------------------------------------------------------
// One iteration, 2 px/thread. acc = x(p) + sum_d s_d(p)*x(p+d)
//                                        + sum_d [valid] s_d(p-d)*x(p-d)
// then out = acc * invm(p). Negative-tap plane reads are shifted (may land in
// a neighboring plane / guard); their values are selected to 0 (cndmask, NaN-
// safe) when the mirror pixel is outside the image. x reads are branch-free
// through guard pads: any OOB x is multiplied by an exactly-zero weight.
// ---------------------------------------------------------------------------
__global__ __launch_bounds__(256) void iter_sym(
    const __half* __restrict__ planes, const float* __restrict__ invm,
    const float* __restrict__ xin, float* __restrict__ xout)
{
    int gid = swz_bid() * 256 + threadIdx.x;
    int p0 = gid * 2;
    int b   = p0 / HW;
    int rem = p0 - b * HW;          // even
    int h   = rem / WW;
    int wc  = rem - h * WW;
    const size_t bHW = (size_t)b * HW;
    const float* xb_ = xin + bHW;

    // rows h-2..h+2, cols rem-2..rem+3, aligned float2 loads
    float xr[5][6];
#pragma unroll
    for (int r = 0; r < 5; ++r) {
        const float* p = xb_ + rem + (r - 2) * WW - 2;
        float2 u0 = *(const float2*)(p);
        float2 u1 = *(const float2*)(p + 2);
        float2 u2 = *(const float2*)(p + 4);
        xr[r][0] = u0.x; xr[r][1] = u0.y;
        xr[r][2] = u1.x; xr[r][3] = u1.y;
        xr[r][4] = u2.x; xr[r][5] = u2.y;
    }

    float acc0 = xr[2][2];          // center tap: a == 1 exactly
    float acc1 = xr[2][3];
#pragma unroll
    for (int t = 13; t < K2; ++t) {
        const int dr = t / KK - RR;          // 0..2
        const int dc = t % KK - RR;          // -2..2 (lex-positive d)
        const __half* pl = planes + (size_t)(t - 13) * NP + bHW + rem;

        // positive tap: s_d(p), aligned half2; OOB already stored as 0
        float2 w = __half22float2(*(const __half2*)pl);
        acc0 = fmaf(w.x, xr[2 + dr][2 + dc], acc0);
        acc1 = fmaf(w.y, xr[2 + dr][3 + dc], acc1);

        // negative tap: s_d(p-d) (shifted read), predicate the mirror pixel
        const int shift = -(dr * WW + dc);
        float s0 = __half2float(pl[shift]);
        float s1 = __half2float(pl[shift + 1]);
        bool ok0 = (dr == 0 || h >= dr) && ((unsigned)(wc - dc) < WW);
        bool ok1 = (dr == 0 || h >= dr) && ((unsigned)(wc + 1 - dc) < WW);
        acc0 = fmaf(ok0 ? s0 : 0.f, xr[2 - dr][2 - dc], acc0);
        acc1 = fmaf(ok1 ? s1 : 0.f, xr[2 - dr][3 - dc], acc1);
    }

    float2 im = *(const float2*)(invm + bHW + rem);
    *(float2*)(xout + bHW + rem) = make_float2(acc0 * im.x, acc1 * im.y);
}

extern "C" void kernel_launch(void* const* d_in, const int* in_sizes, int n_in,
                              void* d_out, int out_size, void* d_ws, size_t ws_size,
                              hipStream_t stream)
{
    const float* img  = (const float*)d_in[0];
    const float* feat = (const float*)d_in[1];
    const float* mask = (const float*)d_in[2];
    float* out = (float*)d_out;

    // ws: [ guard 2KB | planes: 12*NP halves (~14.2MB) | invm: NP f32 (~2.4MB)
    //       | PADF | xa | PADF | xb | PADF ]
    __half* planes = (__half*)d_ws + GUARDH;
    float* invm = (float*)(planes + (size_t)12 * NP);
    float* fbase = invm + NP;
    float* xa = fbase + PADF;
    float* xb = xa + (size_t)NP + PADF;

    prep_sym<<<GRID, 256, 0, stream>>>(img, feat, mask, planes, invm, xa);

    float* cur = xa;
    float* nxt = xb;
    for (int it = 0; it < NITER - 1; ++it) {
        iter_sym<<<GRID, 256, 0, stream>>>(planes, invm, cur, nxt);
        float* t = cur; cur = nxt; nxt = t;
    }
    iter_sym<<<GRID, 256, 0, stream>>>(planes, invm, cur, out);
}